// Round 1
// baseline (378.601 us; speedup 1.0000x reference)
//
#include <hip/hip_runtime.h>
#include <stdint.h>

#define NB 2
#define CH 384
#define NH 8
#define CPH 48
#define IMG 128
#define HW 16384

typedef float f32x4 __attribute__((ext_vector_type(4)));
typedef short bf16x8 __attribute__((ext_vector_type(8)));
typedef short short4v __attribute__((ext_vector_type(4)));

__device__ inline unsigned short f2bf(float f){
    unsigned u = __builtin_bit_cast(unsigned, f);
    u += 0x7FFFu + ((u >> 16) & 1u);
    return (unsigned short)(u >> 16);
}
__device__ inline float bf2f(unsigned short h){
    unsigned u = ((unsigned)h) << 16;
    return __builtin_bit_cast(float, u);
}

// ---------------------------------------------------------------------------
// conv8: 3x3 dwconv for 8 consecutive pixels of one image row, one channel.
// Row clamp uses in-bounds address + zero multiplier (no OOB ever formed).
// Column halos via guarded scalar loads (L1-resident).
// ---------------------------------------------------------------------------
__device__ __forceinline__ void conv8(const float* __restrict__ pl,
                                      const float* w9, int x, int y, float* o)
{
#pragma unroll
    for (int j = 0; j < 8; ++j) o[j] = 0.f;
#pragma unroll
    for (int dy = 0; dy < 3; ++dy) {
        const int yy = y + dy - 1;
        const float vm = (yy >= 0 && yy < IMG) ? 1.f : 0.f;
        const int yc = yy < 0 ? 0 : (yy > IMG - 1 ? IMG - 1 : yy);
        const float* row = pl + yc * IMG;
        float4 A  = *(const float4*)(row + x);
        float4 Bv = *(const float4*)(row + x + 4);
        float lf = (x > 0)       ? row[x - 1] * vm : 0.f;
        float rt = (x < IMG - 8) ? row[x + 8] * vm : 0.f;
        A.x *= vm; A.y *= vm; A.z *= vm; A.w *= vm;
        Bv.x *= vm; Bv.y *= vm; Bv.z *= vm; Bv.w *= vm;
        const float a0 = w9[dy * 3], a1 = w9[dy * 3 + 1], a2 = w9[dy * 3 + 2];
        o[0] += a0 * lf   + a1 * A.x  + a2 * A.y;
        o[1] += a0 * A.x  + a1 * A.y  + a2 * A.z;
        o[2] += a0 * A.y  + a1 * A.z  + a2 * A.w;
        o[3] += a0 * A.z  + a1 * A.w  + a2 * Bv.x;
        o[4] += a0 * A.w  + a1 * Bv.x + a2 * Bv.y;
        o[5] += a0 * Bv.x + a1 * Bv.y + a2 * Bv.z;
        o[6] += a0 * Bv.y + a1 * Bv.z + a2 * Bv.w;
        o[7] += a0 * Bv.z + a1 * Bv.w + a2 * rt;
    }
}

__device__ __forceinline__ void packhl(const float* o, bf16x8& hi, bf16x8& lo,
                                       float& sq)
{
#pragma unroll
    for (int j = 0; j < 8; ++j) {
        sq += o[j] * o[j];
        unsigned short hh = f2bf(o[j]);
        hi[j] = (short)hh;
        lo[j] = (short)f2bf(o[j] - bf2f(hh));
    }
}

// ---------------------------------------------------------------------------
// k_gramf: fused {dwconv3x3(q), dwconv3x3(k)} -> hi/lo bf16 split -> S += q.kT
// Also accumulates per-channel sum-of-squares (norms) via LDS + atomics.
// Block (s, bh): image rows 4s..4s+3 of head (bh) -- conv outputs never touch
// HBM (saves the 100 MB write + 100 MB read round-trip of the old pipeline).
// ---------------------------------------------------------------------------
__global__ __launch_bounds__(256) void k_gramf(
    const float* __restrict__ qf, const float* __restrict__ kf,
    const float* __restrict__ wq, const float* __restrict__ wk,
    float* __restrict__ Sg, float* __restrict__ ssqg)
{
    __shared__ float sred[4][2304];
    __shared__ float ssr[4][96];
    const int t = threadIdx.x;
    const int s = blockIdx.x, bh = blockIdx.y;
    const int wid = t >> 6, lane = t & 63, quad = lane >> 4, l15 = lane & 15;
    const int b = bh >> 3, h = bh & 7;
    const int y = s * 4 + wid;          // image row handled by this wave

    const float* qpl[3];
    const float* kpl[3];
    float wqr[3][9], wkr[3][9];
#pragma unroll
    for (int i = 0; i < 3; ++i) {
        const int c = h * CPH + i * 16 + l15;
        qpl[i] = qf + (size_t)(b * CH + c) * HW;
        kpl[i] = kf + (size_t)(b * CH + c) * HW;
#pragma unroll
        for (int j = 0; j < 9; ++j) {
            wqr[i][j] = wq[c * 9 + j];
            wkr[i][j] = wk[c * 9 + j];
        }
    }

    f32x4 acc[3][3];
#pragma unroll
    for (int i = 0; i < 3; ++i)
#pragma unroll
        for (int j = 0; j < 3; ++j) acc[i][j] = (f32x4){0.f, 0.f, 0.f, 0.f};
    float sqq[3] = {0.f, 0.f, 0.f}, sqk[3] = {0.f, 0.f, 0.f};

    for (int ks = 0; ks < 4; ++ks) {
        const int x = ks * 32 + quad * 8;
        bf16x8 qh[3], ql_[3], kh[3], kl[3];
#pragma unroll
        for (int i = 0; i < 3; ++i) {
            float o[8];
            conv8(qpl[i], wqr[i], x, y, o);
            packhl(o, qh[i], ql_[i], sqq[i]);
            conv8(kpl[i], wkr[i], x, y, o);
            packhl(o, kh[i], kl[i], sqk[i]);
        }
#pragma unroll
        for (int ci = 0; ci < 3; ++ci)
#pragma unroll
            for (int di = 0; di < 3; ++di) {
                acc[ci][di] = __builtin_amdgcn_mfma_f32_16x16x32_bf16(qh[ci],  kh[di], acc[ci][di], 0, 0, 0);
                acc[ci][di] = __builtin_amdgcn_mfma_f32_16x16x32_bf16(qh[ci],  kl[di], acc[ci][di], 0, 0, 0);
                acc[ci][di] = __builtin_amdgcn_mfma_f32_16x16x32_bf16(ql_[ci], kh[di], acc[ci][di], 0, 0, 0);
            }
    }

    // per-channel ssq: reduce across the 4 quads (same channel, different px)
#pragma unroll
    for (int i = 0; i < 3; ++i) {
#pragma unroll
        for (int off = 16; off <= 32; off <<= 1) {
            sqq[i] += __shfl_xor(sqq[i], off);
            sqk[i] += __shfl_xor(sqk[i], off);
        }
        if (lane < 16) {
            ssr[wid][i * 16 + l15]      = sqq[i];
            ssr[wid][48 + i * 16 + l15] = sqk[i];
        }
    }

#pragma unroll
    for (int ci = 0; ci < 3; ++ci)
#pragma unroll
        for (int di = 0; di < 3; ++di)
#pragma unroll
            for (int r = 0; r < 4; ++r)
                sred[wid][(ci * 16 + quad * 4 + r) * 48 + di * 16 + l15] = acc[ci][di][r];
    __syncthreads();

    if (t < 96)
        atomicAdd(&ssqg[(size_t)bh * 96 + t],
                  ssr[0][t] + ssr[1][t] + ssr[2][t] + ssr[3][t]);

    float* Sbh = Sg + (size_t)bh * 2304;
#pragma unroll
    for (int i = 0; i < 9; ++i) {
        int e = t * 9 + i;
        atomicAdd(&Sbh[e], sred[0][e] + sred[1][e] + sred[2][e] + sred[3][e]);
    }
}

// ---------------------------------------------------------------------------
// k_conv3v: dwconv3x3 for V only (bf16 out). Same coalesced row-pair scheme.
// ---------------------------------------------------------------------------
__global__ __launch_bounds__(256) void k_conv3v(
    const float* __restrict__ vf, const float* __restrict__ wv,
    unsigned short* __restrict__ Vc)
{
    const int bc = blockIdx.x;           // b*384+ch
    const int ch = bc % CH;
    const float* plane = vf + (size_t)bc * HW;
    const float* wp9 = wv + ch * 9;
    unsigned short* oh = Vc + (size_t)bc * HW;

    float w9[9];
#pragma unroll
    for (int i = 0; i < 9; ++i) w9[i] = wp9[i];

    const int t = threadIdx.x;
    const int wvid = t >> 6, lane = t & 63;
    const int rb = lane >> 5, cx = lane & 31;

    for (int pass = 0; pass < 16; ++pass) {
        const int y = wvid * 32 + pass * 2 + rb;
        float o0 = 0.f, o1 = 0.f, o2 = 0.f, o3 = 0.f;
#pragma unroll
        for (int dy = 0; dy < 3; ++dy) {
            const int yy = y + dy - 1;
            const float vm = (yy >= 0 && yy < IMG) ? 1.f : 0.f;
            const int yc = yy < 0 ? 0 : (yy > IMG - 1 ? IMG - 1 : yy);
            float4 r4 = *(const float4*)(plane + yc * IMG + 4 * cx);
            r4.x *= vm; r4.y *= vm; r4.z *= vm; r4.w *= vm;
            float lf = __shfl(r4.w, (lane + 63) & 63);
            if (cx == 0) lf = 0.f;
            float rt = __shfl(r4.x, (lane + 1) & 63);
            if (cx == 31) rt = 0.f;
            const float a0 = w9[dy * 3], a1 = w9[dy * 3 + 1], a2 = w9[dy * 3 + 2];
            o0 += a0 * lf   + a1 * r4.x + a2 * r4.y;
            o1 += a0 * r4.x + a1 * r4.y + a2 * r4.z;
            o2 += a0 * r4.y + a1 * r4.z + a2 * r4.w;
            o3 += a0 * r4.z + a1 * r4.w + a2 * rt;
        }
        short4v pv = {(short)f2bf(o0), (short)f2bf(o1), (short)f2bf(o2), (short)f2bf(o3)};
        *(short4v*)(oh + y * IMG + 4 * cx) = pv;
    }
}

// ---------------------------------------------------------------------------
// k_attn: per attn row: normalize, rank, 4 nested-topk softmaxes -> M
// ---------------------------------------------------------------------------
__global__ void k_attn(const float* __restrict__ Sg, const float* __restrict__ ssqg,
                       const float* __restrict__ temp, const float* __restrict__ aw,
                       float* __restrict__ Mg)
{
    const int t = threadIdx.x;
    const int r = blockIdx.x * 4 + (t >> 6);
    const int lane = t & 63;
    const int c = r % 48, h = (r / 48) % NH, b = r / (48 * NH);
    const float* Srow = Sg + ((size_t)(b * NH + h) * 48 + c) * 48;
    const float* sq = ssqg + (size_t)(b * NH + h) * 96;

    float v = -3.0e38f;
    if (lane < 48) {
        float nq = fmaxf(sqrtf(sq[c]), 1e-12f);
        float nk = fmaxf(sqrtf(sq[48 + lane]), 1e-12f);
        v = Srow[lane] / (nq * nk) * temp[h];
    }
    float m = v;
#pragma unroll
    for (int off = 32; off; off >>= 1) m = fmaxf(m, __shfl_xor(m, off));
    int rank = 0;
    for (int e = 0; e < 48; ++e) {
        float ve = __shfl(v, e);
        rank += ((ve > v) || (ve == v && e < lane)) ? 1 : 0;
    }
    float ed = (lane < 48) ? __expf(v - m) : 0.f;
    const int K4[4] = {24, 32, 36, 38};
    float f = 0.f;
#pragma unroll
    for (int i = 0; i < 4; ++i) {
        float x = (rank < K4[i]) ? ed : 0.f;
#pragma unroll
        for (int off = 32; off; off >>= 1) x += __shfl_xor(x, off);
        if (rank < K4[i]) f += aw[i] / x;
    }
    if (lane < 48) Mg[((size_t)(b * NH + h) * 48 + c) * 48 + lane] = ed * f;
}

// ---------------------------------------------------------------------------
// k_w2: W2[b][co][gd] = sum_c Wproj[co][h*48+c] * M[b,h][c][d]  -> bf16
// ---------------------------------------------------------------------------
__global__ void k_w2(const float* __restrict__ wproj, const float* __restrict__ Mg,
                     unsigned short* __restrict__ W2)
{
    int idx = blockIdx.x * 256 + threadIdx.x;
    int gd = idx % 384; int co = (idx / 384) % 384; int b = idx / (384 * 384);
    int h = gd / 48, d = gd % 48;
    const float* wp = wproj + (size_t)co * 384 + h * 48;
    const float* Mp = Mg + (size_t)(b * NH + h) * 2304 + d;
    float s = 0.f;
#pragma unroll
    for (int cc = 0; cc < 48; ++cc) s += wp[cc] * Mp[cc * 48];
    W2[idx] = f2bf(s);
}

// ---------------------------------------------------------------------------
// k_trans: Vc[b][ch][n] -> Vct[b][n][ch]  (64x64 LDS tiles)
// ---------------------------------------------------------------------------
__global__ __launch_bounds__(256) void k_trans(const unsigned short* __restrict__ Vc,
                                               unsigned short* __restrict__ Vct)
{
    __shared__ unsigned short S[64][66];
    const int nt = blockIdx.x, ct = blockIdx.y, b = blockIdx.z;
    const int t = threadIdx.x, r = t >> 2, seg = t & 3;
    const unsigned short* src = Vc + (size_t)(b * CH + ct * 64 + r) * HW + nt * 64 + seg * 16;
    *(bf16x8*)&S[r][seg * 16]     = *(const bf16x8*)src;
    *(bf16x8*)&S[r][seg * 16 + 8] = *(const bf16x8*)(src + 8);
    __syncthreads();
    unsigned short tmp[16];
#pragma unroll
    for (int i = 0; i < 16; ++i) tmp[i] = S[seg * 16 + i][r];
    unsigned short* dst = Vct + ((size_t)b * HW + nt * 64 + r) * CH + ct * 64 + seg * 16;
    *(bf16x8*)dst       = *(const bf16x8*)&tmp[0];
    *(bf16x8*)(dst + 8) = *(const bf16x8*)&tmp[8];
}

// ---------------------------------------------------------------------------
// k_gemm2: out[b] = W2[b] (384x384) @ Vct (LDS-free MFMA GEMM)
// ---------------------------------------------------------------------------
__global__ __launch_bounds__(256) void k_gemm2(const unsigned short* __restrict__ W2,
        const unsigned short* __restrict__ Vct, float* __restrict__ out)
{
    const int t = threadIdx.x;
    const int y = blockIdx.x, mt = blockIdx.y, b = blockIdx.z;
    const int wid = t >> 6, lane = t & 63, quad = lane >> 4, l15 = lane & 15;
    const int wm = wid >> 1, wn = wid & 1;

    f32x4 acc[4][4];
#pragma unroll
    for (int i = 0; i < 4; ++i)
#pragma unroll
        for (int j = 0; j < 4; ++j) acc[i][j] = (f32x4){0.f, 0.f, 0.f, 0.f};

    const unsigned short* Ab[4];
    const unsigned short* Bb[4];
#pragma unroll
    for (int i = 0; i < 4; ++i) {
        Ab[i] = W2 + (size_t)(b * CH + mt * 128 + wm * 64 + i * 16 + l15) * CH + quad * 8;
        Bb[i] = Vct + ((size_t)b * HW + y * IMG + wn * 64 + i * 16 + l15) * CH + quad * 8;
    }

    for (int kt = 0; kt < 12; ++kt) {
        const int K0 = kt * 32;
        bf16x8 af[4], bfr[4];
#pragma unroll
        for (int i = 0; i < 4; ++i) af[i]  = *(const bf16x8*)(Ab[i] + K0);
#pragma unroll
        for (int i = 0; i < 4; ++i) bfr[i] = *(const bf16x8*)(Bb[i] + K0);
#pragma unroll
        for (int mi = 0; mi < 4; ++mi)
#pragma unroll
            for (int ni = 0; ni < 4; ++ni)
                acc[mi][ni] = __builtin_amdgcn_mfma_f32_16x16x32_bf16(af[mi], bfr[ni], acc[mi][ni], 0, 0, 0);
    }
#pragma unroll
    for (int mi = 0; mi < 4; ++mi)
#pragma unroll
        for (int ni = 0; ni < 4; ++ni)
#pragma unroll
            for (int r = 0; r < 4; ++r) {
                int co = mt * 128 + wm * 64 + mi * 16 + quad * 4 + r;
                int n  = y * IMG + wn * 64 + ni * 16 + l15;
                out[(size_t)(b * CH + co) * HW + n] = acc[mi][ni][r];
            }
}

// ---------------------------------------------------------------------------
extern "C" void kernel_launch(void* const* d_in, const int* in_sizes, int n_in,
                              void* d_out, int out_size, void* d_ws, size_t ws_size,
                              hipStream_t stream)
{
    const float* k_fea = (const float*)d_in[0];
    const float* v_fea = (const float*)d_in[1];
    const float* q_fea = (const float*)d_in[2];
    const float* wq = (const float*)d_in[3];
    const float* wk = (const float*)d_in[4];
    const float* wv = (const float*)d_in[5];
    const float* wproj = (const float*)d_in[6];
    const float* temp = (const float*)d_in[7];
    const float* aw = (const float*)d_in[8];
    float* out = (float*)d_out;

    char* ws = (char*)d_ws;
    float* Sg   = (float*)ws;                              // 147456 B
    float* ssqg = (float*)(ws + 147456);                   // 6144 B
    float* Mg   = (float*)(ws + 153600);                   // 147456 B
    unsigned short* W2 = (unsigned short*)(ws + 301056);   // 589824 B

    const size_t PLANE_BYTES = (size_t)NB * CH * HW * 2;   // 25165824 B
    unsigned short* Vc  = (unsigned short*)(ws + 890880);
    unsigned short* Vct = (unsigned short*)(ws + 890880 + PLANE_BYTES);

    // zero Sg + ssqg (contiguous) -- both are atomic-accumulated
    hipMemsetAsync(Sg, 0, 153600, stream);
    k_conv3v<<<768, 256, 0, stream>>>(v_fea, wv, Vc);
    k_gramf<<<dim3(32, 16), 256, 0, stream>>>(q_fea, k_fea, wq, wk, Sg, ssqg);
    k_attn<<<192, 256, 0, stream>>>(Sg, ssqg, temp, aw, Mg);
    k_w2<<<1152, 256, 0, stream>>>(wproj, Mg, W2);
    k_trans<<<dim3(256, 6, 2), 256, 0, stream>>>(Vc, Vct);
    k_gemm2<<<dim3(128, 3, 2), 256, 0, stream>>>(W2, Vct, out);
}

// Round 2
// 335.159 us; speedup vs baseline: 1.1296x; 1.1296x over previous
//
#include <hip/hip_runtime.h>
#include <stdint.h>

#define NB 2
#define CH 384
#define NH 8
#define CPH 48
#define IMG 128
#define HW 16384

typedef float f32x4 __attribute__((ext_vector_type(4)));
typedef short bf16x8 __attribute__((ext_vector_type(8)));
typedef short short4v __attribute__((ext_vector_type(4)));

__device__ inline unsigned short f2bf(float f){
    unsigned u = __builtin_bit_cast(unsigned, f);
    u += 0x7FFFu + ((u >> 16) & 1u);
    return (unsigned short)(u >> 16);
}
__device__ inline float bf2f(unsigned short h){
    unsigned u = ((unsigned)h) << 16;
    return __builtin_bit_cast(float, u);
}

__device__ __forceinline__ void packhl(const float* o, bf16x8& hi, bf16x8& lo,
                                       float& sq)
{
#pragma unroll
    for (int j = 0; j < 8; ++j) {
        sq += o[j] * o[j];
        unsigned short hh = f2bf(o[j]);
        hi[j] = (short)hh;
        lo[j] = (short)f2bf(o[j] - bf2f(hh));
    }
}

// ---------------------------------------------------------------------------
// k_gramf2: fused dwconv3x3(q,k) + hi/lo bf16 split + S += q.kT, LDS-bridged.
// Block (s, bh): image rows {2s, 2s+1} of head bh.
//   Phase A (per row): 256 threads coalesced-conv 96 channel-rows (48 q + 48 k)
//     -> hi/lo bf16 into 48 KB LDS row buffer (XOR-swizzled, T2).
//   Phase B (per row): wave w = one 32-px K-step; swizzled ds_read_b128
//     fragments; 9 pairs x 3 MFMA (hi*hi + hi*lo + lo*hi).
// Conv is fully coalesced (16 threads x 8px = 512B/channel-row), halos via
// in-wave shfl, weights staged in LDS (no 54-VGPR weight file -> occupancy).
// sred reuses the conv buffer (time-disjoint).
// ---------------------------------------------------------------------------
__global__ __launch_bounds__(256, 3) void k_gramf2(
    const float* __restrict__ qf, const float* __restrict__ kf,
    const float* __restrict__ wq, const float* __restrict__ wk,
    float* __restrict__ Sg, float* __restrict__ ssqg)
{
    __shared__ char smem[49152];     // row buffer (conv) / sred (epilogue)
    __shared__ float ssqL[96];
    __shared__ float wL[864];        // [tensor*432 + ch*9 + j]

    const int t = threadIdx.x;
    const int s = blockIdx.x, bh = blockIdx.y;
    const int wid = t >> 6, lane = t & 63, quad = lane >> 4, l15 = lane & 15;
    const int b = bh >> 3, h = bh & 7;

    // stage weights for this head (q then k) + zero ssq accumulator
    for (int idx = t; idx < 864; idx += 256)
        wL[idx] = (idx < 432) ? wq[h * 432 + idx] : wk[h * 432 + idx - 432];
    if (t < 96) ssqL[t] = 0.f;

    f32x4 acc[3][3];
#pragma unroll
    for (int i = 0; i < 3; ++i)
#pragma unroll
        for (int j = 0; j < 3; ++j) acc[i][j] = (f32x4){0.f, 0.f, 0.f, 0.f};

    const int xg = t & 15;           // x-group: 8 px starting at xg*8
    const int grp = t >> 4;          // channel-row group 0..15

    __syncthreads();

    for (int r = 0; r < 2; ++r) {
        const int y = s * 2 + r;

        // ---- Phase A: conv row y, 96 channel-rows, 6 iterations ----
#pragma unroll
        for (int it = 0; it < 6; ++it) {
            const int tc = it * 16 + grp;          // 0..95
            const int tensor = tc >= 48 ? 1 : 0;
            const int ch = tc - tensor * 48;
            const float* pl = (tensor ? kf : qf) + (size_t)(b * CH + h * CPH + ch) * HW;
            const float* wp = &wL[tensor * 432 + ch * 9];

            float o[8];
#pragma unroll
            for (int j = 0; j < 8; ++j) o[j] = 0.f;
#pragma unroll
            for (int dy = 0; dy < 3; ++dy) {
                const int yy = y + dy - 1;
                const float vm = (yy >= 0 && yy < IMG) ? 1.f : 0.f;
                const int yc = yy < 0 ? 0 : (yy > IMG - 1 ? IMG - 1 : yy);
                const float* row = pl + yc * IMG + xg * 8;
                float4 A  = *(const float4*)row;
                float4 Bv = *(const float4*)(row + 4);
                A.x *= vm; A.y *= vm; A.z *= vm; A.w *= vm;
                Bv.x *= vm; Bv.y *= vm; Bv.z *= vm; Bv.w *= vm;
                float lf = __shfl(Bv.w, (lane + 63) & 63);
                if (xg == 0) lf = 0.f;
                float rt = __shfl(A.x, (lane + 1) & 63);
                if (xg == 15) rt = 0.f;
                const float a0 = wp[dy * 3], a1 = wp[dy * 3 + 1], a2 = wp[dy * 3 + 2];
                o[0] += a0 * lf   + a1 * A.x  + a2 * A.y;
                o[1] += a0 * A.x  + a1 * A.y  + a2 * A.z;
                o[2] += a0 * A.y  + a1 * A.z  + a2 * A.w;
                o[3] += a0 * A.z  + a1 * A.w  + a2 * Bv.x;
                o[4] += a0 * A.w  + a1 * Bv.x + a2 * Bv.y;
                o[5] += a0 * Bv.x + a1 * Bv.y + a2 * Bv.z;
                o[6] += a0 * Bv.y + a1 * Bv.z + a2 * Bv.w;
                o[7] += a0 * Bv.z + a1 * Bv.w + a2 * rt;
            }
            float sq = 0.f;
            bf16x8 hi, lo;
            packhl(o, hi, lo, sq);
            // per-channel-row ssq: reduce across the 16-lane x-group
#pragma unroll
            for (int off = 1; off < 16; off <<= 1) sq += __shfl_xor(sq, off);
            if (xg == 0) ssqL[tc] += sq;
            // swizzled LDS write (hi row rr=tensor*96+ch, lo row rr+48)
            const int rbase = (tensor * 96 + ch) * 256;
            const int xb = (xg * 16) ^ ((ch & 7) << 4);
            *(bf16x8*)(smem + rbase + xb) = hi;
            *(bf16x8*)(smem + rbase + 48 * 256 + xb) = lo;
        }
        __syncthreads();

        // ---- Phase B: MFMA; wave wid handles px [32*wid, 32*wid+32) ----
        {
            const int koff = wid * 64 + quad * 16;
            bf16x8 qh[3], ql_[3], kh[3], kl[3];
#pragma unroll
            for (int i = 0; i < 3; ++i) {
                const int ch = i * 16 + l15;
                const int xb = koff ^ ((ch & 7) << 4);
                const char* base = smem + ch * 256 + xb;
                qh[i]  = *(const bf16x8*)(base);
                ql_[i] = *(const bf16x8*)(base + 48 * 256);
                kh[i]  = *(const bf16x8*)(base + 96 * 256);
                kl[i]  = *(const bf16x8*)(base + 144 * 256);
            }
#pragma unroll
            for (int ci = 0; ci < 3; ++ci)
#pragma unroll
                for (int di = 0; di < 3; ++di) {
                    acc[ci][di] = __builtin_amdgcn_mfma_f32_16x16x32_bf16(qh[ci],  kh[di], acc[ci][di], 0, 0, 0);
                    acc[ci][di] = __builtin_amdgcn_mfma_f32_16x16x32_bf16(qh[ci],  kl[di], acc[ci][di], 0, 0, 0);
                    acc[ci][di] = __builtin_amdgcn_mfma_f32_16x16x32_bf16(ql_[ci], kh[di], acc[ci][di], 0, 0, 0);
                }
        }
        __syncthreads();
    }

    // ---- epilogue: cross-wave reduce (sred aliases conv buffer) ----
    float* sred = (float*)smem;
#pragma unroll
    for (int ci = 0; ci < 3; ++ci)
#pragma unroll
        for (int di = 0; di < 3; ++di)
#pragma unroll
            for (int r = 0; r < 4; ++r)
                sred[wid * 2304 + (ci * 16 + quad * 4 + r) * 48 + di * 16 + l15] = acc[ci][di][r];
    __syncthreads();

    if (t < 96)
        atomicAdd(&ssqg[(size_t)bh * 96 + t], ssqL[t]);

    float* Sbh = Sg + (size_t)bh * 2304;
#pragma unroll
    for (int i = 0; i < 9; ++i) {
        int e = t * 9 + i;
        atomicAdd(&Sbh[e], sred[e] + sred[2304 + e] + sred[4608 + e] + sred[6912 + e]);
    }
}

// ---------------------------------------------------------------------------
// k_conv3v: dwconv3x3 for V only (bf16 out). Coalesced row-pair scheme.
// ---------------------------------------------------------------------------
__global__ __launch_bounds__(256) void k_conv3v(
    const float* __restrict__ vf, const float* __restrict__ wv,
    unsigned short* __restrict__ Vc)
{
    const int bc = blockIdx.x;           // b*384+ch
    const int ch = bc % CH;
    const float* plane = vf + (size_t)bc * HW;
    const float* wp9 = wv + ch * 9;
    unsigned short* oh = Vc + (size_t)bc * HW;

    float w9[9];
#pragma unroll
    for (int i = 0; i < 9; ++i) w9[i] = wp9[i];

    const int t = threadIdx.x;
    const int wvid = t >> 6, lane = t & 63;
    const int rb = lane >> 5, cx = lane & 31;

    for (int pass = 0; pass < 16; ++pass) {
        const int y = wvid * 32 + pass * 2 + rb;
        float o0 = 0.f, o1 = 0.f, o2 = 0.f, o3 = 0.f;
#pragma unroll
        for (int dy = 0; dy < 3; ++dy) {
            const int yy = y + dy - 1;
            const float vm = (yy >= 0 && yy < IMG) ? 1.f : 0.f;
            const int yc = yy < 0 ? 0 : (yy > IMG - 1 ? IMG - 1 : yy);
            float4 r4 = *(const float4*)(plane + yc * IMG + 4 * cx);
            r4.x *= vm; r4.y *= vm; r4.z *= vm; r4.w *= vm;
            float lf = __shfl(r4.w, (lane + 63) & 63);
            if (cx == 0) lf = 0.f;
            float rt = __shfl(r4.x, (lane + 1) & 63);
            if (cx == 31) rt = 0.f;
            const float a0 = w9[dy * 3], a1 = w9[dy * 3 + 1], a2 = w9[dy * 3 + 2];
            o0 += a0 * lf   + a1 * r4.x + a2 * r4.y;
            o1 += a0 * r4.x + a1 * r4.y + a2 * r4.z;
            o2 += a0 * r4.y + a1 * r4.z + a2 * r4.w;
            o3 += a0 * r4.z + a1 * r4.w + a2 * rt;
        }
        short4v pv = {(short)f2bf(o0), (short)f2bf(o1), (short)f2bf(o2), (short)f2bf(o3)};
        *(short4v*)(oh + y * IMG + 4 * cx) = pv;
    }
}

// ---------------------------------------------------------------------------
// k_attn: per attn row: normalize, rank, 4 nested-topk softmaxes -> M
// ---------------------------------------------------------------------------
__global__ void k_attn(const float* __restrict__ Sg, const float* __restrict__ ssqg,
                       const float* __restrict__ temp, const float* __restrict__ aw,
                       float* __restrict__ Mg)
{
    const int t = threadIdx.x;
    const int r = blockIdx.x * 4 + (t >> 6);
    const int lane = t & 63;
    const int c = r % 48, h = (r / 48) % NH, b = r / (48 * NH);
    const float* Srow = Sg + ((size_t)(b * NH + h) * 48 + c) * 48;
    const float* sq = ssqg + (size_t)(b * NH + h) * 96;

    float v = -3.0e38f;
    if (lane < 48) {
        float nq = fmaxf(sqrtf(sq[c]), 1e-12f);
        float nk = fmaxf(sqrtf(sq[48 + lane]), 1e-12f);
        v = Srow[lane] / (nq * nk) * temp[h];
    }
    float m = v;
#pragma unroll
    for (int off = 32; off; off >>= 1) m = fmaxf(m, __shfl_xor(m, off));
    int rank = 0;
    for (int e = 0; e < 48; ++e) {
        float ve = __shfl(v, e);
        rank += ((ve > v) || (ve == v && e < lane)) ? 1 : 0;
    }
    float ed = (lane < 48) ? __expf(v - m) : 0.f;
    const int K4[4] = {24, 32, 36, 38};
    float f = 0.f;
#pragma unroll
    for (int i = 0; i < 4; ++i) {
        float x = (rank < K4[i]) ? ed : 0.f;
#pragma unroll
        for (int off = 32; off; off >>= 1) x += __shfl_xor(x, off);
        if (rank < K4[i]) f += aw[i] / x;
    }
    if (lane < 48) Mg[((size_t)(b * NH + h) * 48 + c) * 48 + lane] = ed * f;
}

// ---------------------------------------------------------------------------
// k_w2: W2[b][co][gd] = sum_c Wproj[co][h*48+c] * M[b,h][c][d]  -> bf16
// ---------------------------------------------------------------------------
__global__ void k_w2(const float* __restrict__ wproj, const float* __restrict__ Mg,
                     unsigned short* __restrict__ W2)
{
    int idx = blockIdx.x * 256 + threadIdx.x;
    int gd = idx % 384; int co = (idx / 384) % 384; int b = idx / (384 * 384);
    int h = gd / 48, d = gd % 48;
    const float* wp = wproj + (size_t)co * 384 + h * 48;
    const float* Mp = Mg + (size_t)(b * NH + h) * 2304 + d;
    float s = 0.f;
#pragma unroll
    for (int cc = 0; cc < 48; ++cc) s += wp[cc] * Mp[cc * 48];
    W2[idx] = f2bf(s);
}

// ---------------------------------------------------------------------------
// k_trans: Vc[b][ch][n] -> Vct[b][n][ch]  (64x64 LDS tiles)
// ---------------------------------------------------------------------------
__global__ __launch_bounds__(256) void k_trans(const unsigned short* __restrict__ Vc,
                                               unsigned short* __restrict__ Vct)
{
    __shared__ unsigned short S[64][66];
    const int nt = blockIdx.x, ct = blockIdx.y, b = blockIdx.z;
    const int t = threadIdx.x, r = t >> 2, seg = t & 3;
    const unsigned short* src = Vc + (size_t)(b * CH + ct * 64 + r) * HW + nt * 64 + seg * 16;
    *(bf16x8*)&S[r][seg * 16]     = *(const bf16x8*)src;
    *(bf16x8*)&S[r][seg * 16 + 8] = *(const bf16x8*)(src + 8);
    __syncthreads();
    unsigned short tmp[16];
#pragma unroll
    for (int i = 0; i < 16; ++i) tmp[i] = S[seg * 16 + i][r];
    unsigned short* dst = Vct + ((size_t)b * HW + nt * 64 + r) * CH + ct * 64 + seg * 16;
    *(bf16x8*)dst       = *(const bf16x8*)&tmp[0];
    *(bf16x8*)(dst + 8) = *(const bf16x8*)&tmp[8];
}

// ---------------------------------------------------------------------------
// k_gemm2: out[b] = W2[b] (384x384) @ Vct (LDS-free MFMA GEMM)
// ---------------------------------------------------------------------------
__global__ __launch_bounds__(256) void k_gemm2(const unsigned short* __restrict__ W2,
        const unsigned short* __restrict__ Vct, float* __restrict__ out)
{
    const int t = threadIdx.x;
    const int y = blockIdx.x, mt = blockIdx.y, b = blockIdx.z;
    const int wid = t >> 6, lane = t & 63, quad = lane >> 4, l15 = lane & 15;
    const int wm = wid >> 1, wn = wid & 1;

    f32x4 acc[4][4];
#pragma unroll
    for (int i = 0; i < 4; ++i)
#pragma unroll
        for (int j = 0; j < 4; ++j) acc[i][j] = (f32x4){0.f, 0.f, 0.f, 0.f};

    const unsigned short* Ab[4];
    const unsigned short* Bb[4];
#pragma unroll
    for (int i = 0; i < 4; ++i) {
        Ab[i] = W2 + (size_t)(b * CH + mt * 128 + wm * 64 + i * 16 + l15) * CH + quad * 8;
        Bb[i] = Vct + ((size_t)b * HW + y * IMG + wn * 64 + i * 16 + l15) * CH + quad * 8;
    }

    for (int kt = 0; kt < 12; ++kt) {
        const int K0 = kt * 32;
        bf16x8 af[4], bfr[4];
#pragma unroll
        for (int i = 0; i < 4; ++i) af[i]  = *(const bf16x8*)(Ab[i] + K0);
#pragma unroll
        for (int i = 0; i < 4; ++i) bfr[i] = *(const bf16x8*)(Bb[i] + K0);
#pragma unroll
        for (int mi = 0; mi < 4; ++mi)
#pragma unroll
            for (int ni = 0; ni < 4; ++ni)
                acc[mi][ni] = __builtin_amdgcn_mfma_f32_16x16x32_bf16(af[mi], bfr[ni], acc[mi][ni], 0, 0, 0);
    }
#pragma unroll
    for (int mi = 0; mi < 4; ++mi)
#pragma unroll
        for (int ni = 0; ni < 4; ++ni)
#pragma unroll
            for (int r = 0; r < 4; ++r) {
                int co = mt * 128 + wm * 64 + mi * 16 + quad * 4 + r;
                int n  = y * IMG + wn * 64 + ni * 16 + l15;
                out[(size_t)(b * CH + co) * HW + n] = acc[mi][ni][r];
            }
}

// ---------------------------------------------------------------------------
extern "C" void kernel_launch(void* const* d_in, const int* in_sizes, int n_in,
                              void* d_out, int out_size, void* d_ws, size_t ws_size,
                              hipStream_t stream)
{
    const float* k_fea = (const float*)d_in[0];
    const float* v_fea = (const float*)d_in[1];
    const float* q_fea = (const float*)d_in[2];
    const float* wq = (const float*)d_in[3];
    const float* wk = (const float*)d_in[4];
    const float* wv = (const float*)d_in[5];
    const float* wproj = (const float*)d_in[6];
    const float* temp = (const float*)d_in[7];
    const float* aw = (const float*)d_in[8];
    float* out = (float*)d_out;

    char* ws = (char*)d_ws;
    float* Sg   = (float*)ws;                              // 147456 B
    float* ssqg = (float*)(ws + 147456);                   // 6144 B
    float* Mg   = (float*)(ws + 153600);                   // 147456 B
    unsigned short* W2 = (unsigned short*)(ws + 301056);   // 589824 B

    const size_t PLANE_BYTES = (size_t)NB * CH * HW * 2;   // 25165824 B
    unsigned short* Vc  = (unsigned short*)(ws + 890880);
    unsigned short* Vct = (unsigned short*)(ws + 890880 + PLANE_BYTES);

    // zero Sg + ssqg (contiguous) -- both are atomic-accumulated
    hipMemsetAsync(Sg, 0, 153600, stream);
    k_conv3v<<<768, 256, 0, stream>>>(v_fea, wv, Vc);
    k_gramf2<<<dim3(64, 16), 256, 0, stream>>>(q_fea, k_fea, wq, wk, Sg, ssqg);
    k_attn<<<192, 256, 0, stream>>>(Sg, ssqg, temp, aw, Mg);
    k_w2<<<1152, 256, 0, stream>>>(wproj, Mg, W2);
    k_trans<<<dim3(256, 6, 2), 256, 0, stream>>>(Vc, Vct);
    k_gemm2<<<dim3(128, 3, 2), 256, 0, stream>>>(W2, Vct, out);
}